// Round 6
// baseline (107.471 us; speedup 1.0000x reference)
//
#include <hip/hip_runtime.h>

#define NPTS 8192
#define DIM 64
#define EPSF 1e-7f
#define LN2F 0.69314718055994531f
#define NBLK 1056      // sum_{by=0}^{31} (64 - 2*by)

typedef unsigned short u16;
typedef __attribute__((ext_vector_type(8))) short bf16x8;   // 8 bf16 (4 VGPRs)
typedef __attribute__((ext_vector_type(8))) unsigned short u16x8;
typedef __attribute__((ext_vector_type(4))) float f32x4;
typedef __attribute__((ext_vector_type(2))) float f32x2;

// ---- kernel 1: x -> bf16 (round-to-nearest); meta = {-sq/2, 1/(1-sq), -4/(1-sq), label}
__global__ void prep_kernel(const float* __restrict__ x, const int* __restrict__ labels,
                            u16* __restrict__ hi,
                            float4* __restrict__ meta,
                            float* __restrict__ out) {
    int g = blockIdx.x * blockDim.x + threadIdx.x;   // 0 .. NPTS*8-1
    int row = g >> 3, sub = g & 7;
    const float* xp = x + row * DIM + sub * 8;
    float v[8];
    float s = 0.f;
#pragma unroll
    for (int k = 0; k < 8; k++) { v[k] = xp[k]; s = fmaf(v[k], v[k], s); }
    s += __shfl_xor(s, 1);
    s += __shfl_xor(s, 2);
    s += __shfl_xor(s, 4);
    u16x8 h;
#pragma unroll
    for (int k = 0; k < 8; k++) {
        unsigned int bits = __float_as_uint(v[k]);
        unsigned int r = bits + 0x7FFFu + ((bits >> 16) & 1u);   // RTN-even bf16
        h[k] = (u16)(r >> 16);
    }
    *(u16x8*)(hi + row * DIM + sub * 8) = h;
    if (sub == 0) {
        float r = 1.0f / (1.0f - s);
        meta[row] = make_float4(-0.5f * s, r, -4.0f * r, (float)labels[row]);
    }
    if (g == 3) out[0] = 0.f;
}

// C(b) = number of active tiles with by < b
__device__ __forceinline__ int cumtiles(int b) { return 65 * b - b * b; }

// ---- kernel 2: triangular fused MFMA Gram + hyperbolic epilogue -------------
// R23: de-convoyed 1-WAVE blocks. Evidence (R19-R22): wall ~40us invariant to
// epilogue/atomics/LDS/grid; waves stall 83% of residency; all prior variants
// ran 4-wave lockstep blocks -> every co-resident wave hits its per-iter
// vmcnt window simultaneously (load convoy into one TA/L2 port, collective
// stall). This version: (a) 64-thread blocks, grid 8448, no barriers;
// (b) per-block t-phase rotation (t2 = (t + b&7) & 7) so co-resident waves
// touch different j-groups at any instant; (c) T accumulated as PRODUCTS of
// selected w1 (log2 taken once per row at end / once per column-group per t:
// 16 v_log per wave-block instead of 64; products of <=8 terms, w1<=362,
// max ~3e20 -- f32-safe). Output atomic-free per-block slices.
__global__ void __launch_bounds__(64, 4) pair_mfma(
        const u16* __restrict__ hi,
        const float4* __restrict__ meta,
        float* __restrict__ Pi, float* __restrict__ Pj) {
    __shared__ float slabS[128], slabT[128];   // 1 KB: this wave's j-column partials

    int lane = threadIdx.x;
    int quad = lane >> 4, l15 = lane & 15;

    int b = blockIdx.x;
    int w = b & 3;            // sub-wave: which 32-row strip of the 128-row tile
    int bid2 = b >> 2;
    int half = bid2 & 1;
    int bid = bid2 >> 1;
    int by = (int)((65.0f - __builtin_amdgcn_sqrtf(4225.0f - 4.0f * (float)bid)) * 0.5f);
    while (cumtiles(by + 1) <= bid) by++;
    while (cumtiles(by) > bid) by--;
    int off = bid - cumtiles(by);
    int bx = 2 * by + off;
    bool full = (off >= 2);

    int i0 = bx * 128 + w * 32;
    int jbase = by * 256 + half * 128;   // this block's 8 j-groups start here
    int offs = b & 7;                    // t-phase rotation (de-convoy)

    bf16x8 a_hi[2][2];
#pragma unroll
    for (int it = 0; it < 2; it++)
#pragma unroll
        for (int ks = 0; ks < 2; ks++) {
            int aoff = (i0 + it * 16 + l15) * DIM + ks * 32 + quad * 8;
            a_hi[it][ks] = *(const bf16x8*)(hi + aoff);
        }

    f32x4 hsqi4[2];          // -sq_i/2 for this lane's 8 rows (C-init vector)
    f32x2 rcp2[4];           // 1/(1-sq_i) packed pairs
    float labi[8];
#pragma unroll
    for (int it = 0; it < 2; it++)
#pragma unroll
        for (int r = 0; r < 4; r++) {
            float4 m = meta[i0 + it * 16 + quad * 4 + r];
            hsqi4[it][r] = m.x;
            rcp2[it * 2 + (r >> 1)][r & 1] = m.y;
            labi[it * 4 + r] = m.w;
        }

    f32x2 Sx2[4], Tp2[4];
#pragma unroll
    for (int k = 0; k < 4; k++) { Sx2[k] = (f32x2){0.f, 0.f}; Tp2[k] = (f32x2){1.f, 1.f}; }

    // register double-buffer: B fragments + meta for the next t (rotated order)
    bf16x8 bh[2][2];
    float4 mjb[2];
    {
        int jg0 = jbase + offs * 16 + l15;
        int boff = jg0 * DIM + quad * 8;
        bh[0][0] = *(const bf16x8*)(hi + boff);
        bh[0][1] = *(const bf16x8*)(hi + boff + 32);
        mjb[0] = meta[jg0];
    }

#pragma unroll 2
    for (int t = 0; t < 8; t++) {
        int cur = t & 1, nxt = cur ^ 1;
        int t2 = (t + offs) & 7;
        if (t < 7) {
            int jgn = jbase + (((t + 1 + offs) & 7) * 16) + l15;
            int boff = jgn * DIM + quad * 8;
            bh[nxt][0] = *(const bf16x8*)(hi + boff);
            bh[nxt][1] = *(const bf16x8*)(hi + boff + 32);
            mjb[nxt] = meta[jgn];
        }
        float4 mj = mjb[cur];    // {hsqj, rcpomj, m4rj, labj}

        f32x2 sSum = (f32x2){0.f, 0.f};
        f32x2 tProd = (f32x2){1.f, 1.f};
#pragma unroll
        for (int it = 0; it < 2; it++) {
            f32x4 acc = hsqi4[it] + mj.x;          // norms folded via C operand
            acc = __builtin_amdgcn_mfma_f32_16x16x32_bf16(a_hi[it][0], bh[cur][0], acc, 0, 0, 0);
            acc = __builtin_amdgcn_mfma_f32_16x16x32_bf16(a_hi[it][1], bh[cur][1], acc, 0, 0, 0);

#pragma unroll
            for (int g = 0; g < 2; g++) {          // packed pairs (rows 2g, 2g+1)
                f32x2 D = (f32x2){acc[2 * g], acc[2 * g + 1]};
                f32x2 u = (D * rcp2[it * 2 + g]) * mj.z;
                u = __builtin_elementwise_max(u, (f32x2){EPSF, EPSF});
                f32x2 arg = u * u + (u + u);
                f32x2 srt = (f32x2){__builtin_amdgcn_sqrtf(arg.x), __builtin_amdgcn_sqrtf(arg.y)};
                f32x2 opu = u + 1.0f;
                f32x2 st = opu - srt;              // exp(-d)
                f32x2 w1 = opu + srt;              // exp(+d), in [1, ~362]
                f32x2 sel;
                sel.x = (mj.w == labi[it * 4 + 2 * g]) ? w1.x : 1.0f;
                sel.y = (mj.w == labi[it * 4 + 2 * g + 1]) ? w1.y : 1.0f;
                Sx2[it * 2 + g] += st;
                Tp2[it * 2 + g] *= sel;            // i-side product across 8 t's
                sSum += st;
                tProd *= sel;                      // j-side product across this lane's 8 rows
            }
        }

        // j-column partials: one log per lane (product of its 8 rows), then
        // cross-quad ADD of logs (product across 32 rows would overflow f32).
        float pS = sSum.x + sSum.y;
        float pT = __builtin_amdgcn_logf(tProd.x * tProd.y);
        pS += __shfl_xor(pS, 16); pS += __shfl_xor(pS, 32);
        pT += __shfl_xor(pT, 16); pT += __shfl_xor(pT, 32);
        if (quad == 0) {
            int c = t2 * 16 + l15;
            slabS[c] = pS;
            slabT[c] = pT;
        }
    }

    // i-side: logs of row-products, then reduce across the 16 j-columns
    float Sx[8], Tx[8];
#pragma unroll
    for (int k = 0; k < 4; k++) {
        Sx[2 * k] = Sx2[k].x; Sx[2 * k + 1] = Sx2[k].y;
        Tx[2 * k] = __builtin_amdgcn_logf(Tp2[k].x);
        Tx[2 * k + 1] = __builtin_amdgcn_logf(Tp2[k].y);
    }
#pragma unroll
    for (int r = 0; r < 8; r++) {
#pragma unroll
        for (int m = 1; m < 16; m <<= 1) {
            Sx[r] += __shfl_xor(Sx[r], m);
            Tx[r] += __shfl_xor(Tx[r], m);
        }
    }
    // plain stores to this block's private slice: Pi[b][S:32 | T:32]
    float* PiB = Pi + (size_t)b * 64;
    if (l15 == 0) {
#pragma unroll
        for (int it = 0; it < 2; it++)
#pragma unroll
            for (int r = 0; r < 4; r++) {
                int rowb = it * 16 + quad * 4 + r;
                PiB[rowb] = Sx[it * 4 + r];
                PiB[32 + rowb] = Tx[it * 4 + r];
            }
    }

    // j-side: flush slab (full tiles only). Single wave: LDS ops in-order,
    // no barrier needed.
    if (full) {
        float* PjB = Pj + (size_t)b * 256;
        PjB[lane]       = slabS[lane];
        PjB[lane + 64]  = slabS[lane + 64];
        PjB[lane + 128] = slabT[lane];
        PjB[lane + 192] = slabT[lane + 64];
    }
}

// ---- kernel 3: gather partials + finalize, 128 blocks x 64 points x 4 slices
__global__ void __launch_bounds__(256) finalize_kernel(
        const float* __restrict__ Pi, const float* __restrict__ Pj,
        const int* __restrict__ labels, float* __restrict__ out) {
    __shared__ int hist[16][16];
    __shared__ float cntf[16];
    __shared__ float redS[4][64], redT[4][64];
    int tid = threadIdx.x;
    hist[tid >> 4][tid & 15] = 0;
    __syncthreads();
    int rep = tid & 15;
    for (int i = tid; i < NPTS; i += 256)
        atomicAdd(&hist[rep][labels[i]], 1);
    __syncthreads();
    if (tid < 16) {
        int s = 0;
#pragma unroll
        for (int k = 0; k < 16; k++) s += hist[k][tid];
        cntf[tid] = (float)(s - 1);
    }

    int slice = tid >> 6, pl = tid & 63;
    int i = blockIdx.x * 64 + pl;
    int bx = i >> 7;
    int r128 = i & 127;
    int wq = r128 >> 5;          // which sub-wave owned this row
    int r32 = i & 31;
    float s = 0.f, t = 0.f;
    // i-side: blocks (by, off=bx-2by), both halves, fixed sub-wave wq
    for (int by = slice; by <= (bx >> 1); by += 4) {
        int bidb = cumtiles(by) + (bx - 2 * by);
        int b0 = (bidb * 2) * 4 + wq;            // half 0
        int b1 = (bidb * 2 + 1) * 4 + wq;        // half 1
        s += Pi[(size_t)b0 * 64 + r32] + Pi[(size_t)b1 * 64 + r32];
        t += Pi[(size_t)b0 * 64 + 32 + r32] + Pi[(size_t)b1 * 64 + 32 + r32];
    }
    // j-side: full blocks (byj, off in [2, 64-2byj), half = bx&1), all 4 sub-waves
    int byj = bx >> 1, halfj = bx & 1;
    int jmax = 64 - 2 * byj;
    int cbase = cumtiles(byj);
    for (int off = 2 + slice; off < jmax; off += 4) {
        int bb = ((cbase + off) * 2 + halfj) * 4;
#pragma unroll
        for (int w2 = 0; w2 < 4; w2++) {
            s += Pj[(size_t)(bb + w2) * 256 + r128];
            t += Pj[(size_t)(bb + w2) * 256 + 128 + r128];
        }
    }
    redS[slice][pl] = s;
    redT[slice][pl] = t;
    __syncthreads();
    if (tid < 64) {
        float S = redS[0][tid] + redS[1][tid] + redS[2][tid] + redS[3][tid];
        float T = redT[0][tid] + redT[1][tid] + redT[2][tid] + redT[3][tid];
        float s0 = __builtin_amdgcn_sqrtf(EPSF * (2.0f + EPSF));
        float st0 = 1.0f + EPSF - s0;                         // self exp(-d) term
        float l20 = __builtin_amdgcn_logf(1.0f + EPSF + s0);  // self log2 term
        int ii = blockIdx.x * 64 + tid;
        float loss = __logf(S - st0) + (T - l20) * LN2F / cntf[labels[ii]];
#pragma unroll
        for (int m = 1; m < 64; m <<= 1) loss += __shfl_xor(loss, m);
        if (tid == 0) atomicAdd(out, loss);
    }
}

extern "C" void kernel_launch(void* const* d_in, const int* in_sizes, int n_in,
                              void* d_out, int out_size, void* d_ws, size_t ws_size,
                              hipStream_t stream) {
    const float* x = (const float*)d_in[0];
    const int* labels = (const int*)d_in[1];

    u16* hi = (u16*)d_ws;                                 // 1 MB
    float4* meta = (float4*)(hi + NPTS * DIM);            // 128 KB
    float* Pi = (float*)(meta + NPTS);                    // 8448*64 floats  (2.2 MB)
    float* Pj = Pi + (size_t)8 * NBLK * 64;               // 8448*256 floats (8.7 MB)

    prep_kernel<<<(NPTS * 8) / 256, 256, 0, stream>>>(x, labels, hi, meta, (float*)d_out);

    pair_mfma<<<8 * NBLK, 64, 0, stream>>>(hi, meta, Pi, Pj);

    finalize_kernel<<<NPTS / 64, 256, 0, stream>>>(Pi, Pj, labels, (float*)d_out);
}